// Round 13
// baseline (428.768 us; speedup 1.0000x reference)
//
#include <hip/hip_runtime.h>
#include <hip/hip_bf16.h>
#include <cstdint>

typedef __bf16 bf16;
typedef bf16 bf16x8 __attribute__((ext_vector_type(8)));
typedef float f32x4 __attribute__((ext_vector_type(4)));

#define MFMA16(a, b, c) __builtin_amdgcn_mfma_f32_16x16x32_bf16((a), (b), (c), 0, 0, 0)

constexpr int D_MODEL = 768;
constexpr int NHEAD = 12;
constexpr int DK = 64;
constexpr int SEQ = 4096;
constexpr int BATCH = 2;
constexpr int MROWS = BATCH * SEQ;  // 8192
constexpr float QSCALE = 0.125f * 1.44269504089f;  // (1/sqrt(dk)) * log2(e)

// ---------------------------------------------------------------- fused QKV projection
// 128x128 tile, 4 waves each 64x64 (acc[4][4]). A-staging converts x fp32->bf16 in-flight.
// V^T stored with seq-columns permuted within each 64-group by sigma(k)=((k&15)<<2)|(k>>4)
// so the attention kernel's P-writes pack into b64 (slot mapping consistent for P and V).
__global__ __launch_bounds__(256, 2) void gemm_qkv(const float* __restrict__ X,
                                                   const float* __restrict__ Wq,
                                                   const float* __restrict__ Wk,
                                                   const float* __restrict__ Wv,
                                                   const float* __restrict__ bq,
                                                   const float* __restrict__ bk,
                                                   const float* __restrict__ bv,
                                                   bf16* __restrict__ Qb,
                                                   bf16* __restrict__ Kb,
                                                   bf16* __restrict__ Vtb) {
    constexpr int LDP = 88;
    __shared__ bf16 Asm[128][LDP];
    __shared__ bf16 Bsm[128][LDP];
    const int tid = threadIdx.x, lane = tid & 63, wid = tid >> 6;
    const int wm = wid >> 1, wn = wid & 1;
    const int m0 = blockIdx.x * 128;
    const int sel = blockIdx.y / 6;
    const int n0 = (blockIdx.y % 6) * 128;
    const float* Bw = sel == 0 ? Wq : (sel == 1 ? Wk : Wv);
    const float* bias = sel == 0 ? bq : (sel == 1 ? bk : bv);

    f32x4 acc[4][4];
#pragma unroll
    for (int i = 0; i < 4; i++)
#pragma unroll
        for (int j = 0; j < 4; j++) acc[i][j] = f32x4{0.f, 0.f, 0.f, 0.f};

    const int rr = tid >> 3, cc = (tid & 7) * 8;
    for (int k0 = 0; k0 < 768; k0 += 64) {
#pragma unroll
        for (int p = 0; p < 4; p++) {
            const float* src = X + (size_t)(m0 + p * 32 + rr) * 768 + k0 + cc;
            const float4 f0 = *reinterpret_cast<const float4*>(src);
            const float4 f1 = *reinterpret_cast<const float4*>(src + 4);
            bf16x8 a8;
            a8[0] = (bf16)f0.x; a8[1] = (bf16)f0.y; a8[2] = (bf16)f0.z; a8[3] = (bf16)f0.w;
            a8[4] = (bf16)f1.x; a8[5] = (bf16)f1.y; a8[6] = (bf16)f1.z; a8[7] = (bf16)f1.w;
            *reinterpret_cast<bf16x8*>(&Asm[p * 32 + rr][cc]) = a8;
        }
#pragma unroll
        for (int p = 0; p < 4; p++) {
            const float* src = Bw + (size_t)(n0 + p * 32 + rr) * 768 + k0 + cc;
            const float4 f0 = *reinterpret_cast<const float4*>(src);
            const float4 f1 = *reinterpret_cast<const float4*>(src + 4);
            bf16x8 b8;
            b8[0] = (bf16)f0.x; b8[1] = (bf16)f0.y; b8[2] = (bf16)f0.z; b8[3] = (bf16)f0.w;
            b8[4] = (bf16)f1.x; b8[5] = (bf16)f1.y; b8[6] = (bf16)f1.z; b8[7] = (bf16)f1.w;
            *reinterpret_cast<bf16x8*>(&Bsm[p * 32 + rr][cc]) = b8;
        }
        __syncthreads();
#pragma unroll
        for (int kk = 0; kk < 64; kk += 32) {
            const int krd = kk + ((lane >> 4) << 3);
            bf16x8 af[4], bfr[4];
#pragma unroll
            for (int i = 0; i < 4; i++)
                af[i] = *reinterpret_cast<const bf16x8*>(&Asm[wm * 64 + i * 16 + (lane & 15)][krd]);
#pragma unroll
            for (int j = 0; j < 4; j++)
                bfr[j] = *reinterpret_cast<const bf16x8*>(&Bsm[wn * 64 + j * 16 + (lane & 15)][krd]);
#pragma unroll
            for (int i = 0; i < 4; i++)
#pragma unroll
                for (int j = 0; j < 4; j++) acc[i][j] = MFMA16(af[i], bfr[j], acc[i][j]);
        }
        __syncthreads();
    }

    const float scale = (sel == 0) ? QSCALE : 1.0f;
    const int rbase = m0 + wm * 64 + ((lane >> 4) << 2);
    const int cbase = n0 + wn * 64 + (lane & 15);
    bf16* obf = sel == 0 ? Qb : (sel == 1 ? Kb : Vtb);
#pragma unroll
    for (int i = 0; i < 4; i++) {
#pragma unroll
        for (int j = 0; j < 4; j++) {
            const int ncol = cbase + j * 16;
            const float bv = bias[ncol];
            const int h = ncol >> 6, d = ncol & 63;
#pragma unroll
            for (int r = 0; r < 4; r++) {
                const int mrow = rbase + i * 16 + r;
                const float v = (acc[i][j][r] + bv) * scale;
                const int b = mrow >> 12, s = mrow & 4095;
                if (sel < 2) {
                    obf[(((size_t)(b * NHEAD + h)) * SEQ + s) * DK + d] = (bf16)v;
                } else {
                    // slot-permuted V^T store (within each 64-key group)
                    const int sp = (s & ~63) | (((s & 15) << 2) | ((s >> 4) & 3));
                    obf[(((size_t)(b * NHEAD + h)) * DK + d) * SEQ + sp] = (bf16)v;
                }
            }
        }
    }
}

// ---------------------------------------------------------------- out projection GEMM
// 128x128 tile (same fabric as gemm_qkv), fp32 epilogue with bias.
__global__ __launch_bounds__(256, 2) void gemm_out(const bf16* __restrict__ A,
                                                   const float* __restrict__ Bw,
                                                   const float* __restrict__ bias,
                                                   float* __restrict__ ofl) {
    constexpr int LDP = 88;
    __shared__ bf16 Asm[128][LDP];
    __shared__ bf16 Bsm[128][LDP];
    const int tid = threadIdx.x, lane = tid & 63, wid = tid >> 6;
    const int wm = wid >> 1, wn = wid & 1;
    const int m0 = blockIdx.x * 128, n0 = blockIdx.y * 128;

    f32x4 acc[4][4];
#pragma unroll
    for (int i = 0; i < 4; i++)
#pragma unroll
        for (int j = 0; j < 4; j++) acc[i][j] = f32x4{0.f, 0.f, 0.f, 0.f};

    const int rr = tid >> 3, cc = (tid & 7) * 8;
    for (int k0 = 0; k0 < 768; k0 += 64) {
#pragma unroll
        for (int p = 0; p < 4; p++)
            *reinterpret_cast<bf16x8*>(&Asm[p * 32 + rr][cc]) =
                *reinterpret_cast<const bf16x8*>(A + (size_t)(m0 + p * 32 + rr) * 768 + k0 + cc);
#pragma unroll
        for (int p = 0; p < 4; p++) {
            const float* src = Bw + (size_t)(n0 + p * 32 + rr) * 768 + k0 + cc;
            const float4 f0 = *reinterpret_cast<const float4*>(src);
            const float4 f1 = *reinterpret_cast<const float4*>(src + 4);
            bf16x8 b8;
            b8[0] = (bf16)f0.x; b8[1] = (bf16)f0.y; b8[2] = (bf16)f0.z; b8[3] = (bf16)f0.w;
            b8[4] = (bf16)f1.x; b8[5] = (bf16)f1.y; b8[6] = (bf16)f1.z; b8[7] = (bf16)f1.w;
            *reinterpret_cast<bf16x8*>(&Bsm[p * 32 + rr][cc]) = b8;
        }
        __syncthreads();
#pragma unroll
        for (int kk = 0; kk < 64; kk += 32) {
            const int krd = kk + ((lane >> 4) << 3);
            bf16x8 af[4], bfr[4];
#pragma unroll
            for (int i = 0; i < 4; i++)
                af[i] = *reinterpret_cast<const bf16x8*>(&Asm[wm * 64 + i * 16 + (lane & 15)][krd]);
#pragma unroll
            for (int j = 0; j < 4; j++)
                bfr[j] = *reinterpret_cast<const bf16x8*>(&Bsm[wn * 64 + j * 16 + (lane & 15)][krd]);
#pragma unroll
            for (int i = 0; i < 4; i++)
#pragma unroll
                for (int j = 0; j < 4; j++) acc[i][j] = MFMA16(af[i], bfr[j], acc[i][j]);
        }
        __syncthreads();
    }

    const int rbase = m0 + wm * 64 + ((lane >> 4) << 2);
    const int cbase = n0 + wn * 64 + (lane & 15);
#pragma unroll
    for (int i = 0; i < 4; i++) {
#pragma unroll
        for (int j = 0; j < 4; j++) {
            const int ncol = cbase + j * 16;
            const float bv = bias[ncol];
#pragma unroll
            for (int r = 0; r < 4; r++) {
                const int mrow = rbase + i * 16 + r;
                ofl[(size_t)mrow * 768 + ncol] = acc[i][j][r] + bv;
            }
        }
    }
}

// ---------------------------------------------------------------- flash attention
// R12 math, K/V LDS ELIMINATED: MFMA K/V fragments are per-lane contiguous 16B in
// Kb/Vtb global layout, so each wave loads them global->register directly (L1 serves
// the 4x intra-block reuse). LDS keeps only wave-local Psm -> ZERO __syncthreads in
// the loop; waves fully independent. kf issued before vf each tile so counted vmcnt
// lets vf stay in flight through softmax. LDS 18.4KB; same proven softmax/P/PV path.
__global__ __launch_bounds__(256, 3) void attn_kernel(const bf16* __restrict__ Qb,
                                                      const bf16* __restrict__ Kb,
                                                      const bf16* __restrict__ Vtb,
                                                      bf16* __restrict__ ctx) {
    __shared__ bf16 Psm[4][32][72];  // per-wave [q][slot]
    const int tid = threadIdx.x, l = tid & 63, w = tid >> 6;
    const int bh = blockIdx.y;
    const int q0 = blockIdx.x * 128;
    const bf16* Qh = Qb + (size_t)bh * SEQ * DK;
    const bf16* Kh = Kb + (size_t)bh * SEQ * DK;
    const bf16* Vth = Vtb + (size_t)bh * DK * SEQ;

    const int rsel = l & 15, csel = l >> 4;

    // Q fragments: 2 halves x 2 k-chunks (pre-scaled by 0.125*log2e in projection)
    bf16x8 qf[2][2];
#pragma unroll
    for (int qi = 0; qi < 2; qi++) {
        const int qr = q0 + w * 32 + qi * 16 + rsel;
#pragma unroll
        for (int kk = 0; kk < 2; kk++)
            qf[qi][kk] = *reinterpret_cast<const bf16x8*>(Qh + (size_t)qr * DK + kk * 32 + csel * 8);
    }

    // ones B-fragment: col 0 (rsel==0) = 1, else 0 -> row-sum accumulator column
    bf16x8 vones;
    {
        const bf16 ov = (rsel == 0) ? (bf16)1.0f : (bf16)0.0f;
#pragma unroll
        for (int j = 0; j < 8; j++) vones[j] = ov;
    }

    float m = -1e30f;
    f32x4 aco[2][4], aco_x[2];
#pragma unroll
    for (int qi = 0; qi < 2; qi++) {
#pragma unroll
        for (int f = 0; f < 4; f++) aco[qi][f] = f32x4{0.f, 0.f, 0.f, 0.f};
        aco_x[qi] = f32x4{0.f, 0.f, 0.f, 0.f};
    }

    // per-lane fragment base addresses
    const bf16* kbase = Kh + (size_t)rsel * DK + csel * 8;           // + (t*64 + f*16)*DK + kk*32
    const bf16* vbase = Vth + (size_t)rsel * SEQ + csel * 8;         // + f2*16*SEQ + t*64 + ph*32

    constexpr int NT = SEQ / 64;
    for (int t = 0; t < NT; ++t) {
        const size_t koff = (size_t)t * 64 * DK;
        const int voff = t * 64;

        // K fragments for this tile (issued FIRST -> QK^T waits only on these)
        bf16x8 kf[2][4];
#pragma unroll
        for (int f = 0; f < 4; f++)
#pragma unroll
            for (int kk = 0; kk < 2; kk++)
                kf[kk][f] = *reinterpret_cast<const bf16x8*>(kbase + koff + (size_t)f * 16 * DK + kk * 32);

        // V fragments (issued second; consumed after softmax -> latency hidden)
        bf16x8 vf[2][4];
#pragma unroll
        for (int ph = 0; ph < 2; ph++)
#pragma unroll
            for (int f2 = 0; f2 < 4; f2++)
                vf[ph][f2] = *reinterpret_cast<const bf16x8*>(vbase + (size_t)f2 * 16 * SEQ + voff + ph * 32);

        // joint QK^T: each kf feeds both halves
        f32x4 s4[2][4];
#pragma unroll
        for (int qi = 0; qi < 2; qi++)
#pragma unroll
            for (int f = 0; f < 4; f++) s4[qi][f] = f32x4{0.f, 0.f, 0.f, 0.f};
#pragma unroll
        for (int kk = 0; kk < 2; kk++) {
#pragma unroll
            for (int f = 0; f < 4; f++) {
                s4[0][f] = MFMA16(qf[0][kk], kf[kk][f], s4[0][f]);
                s4[1][f] = MFMA16(qf[1][kk], kf[kk][f], s4[1][f]);
            }
        }

        // lazy max: per-lane max over all 32 scores + vote; butterfly only on growth
        float tm = s4[0][0][0];
#pragma unroll
        for (int qi = 0; qi < 2; qi++)
#pragma unroll
            for (int f = 0; f < 4; f++)
#pragma unroll
                for (int r = 0; r < 4; r++) tm = fmaxf(tm, s4[qi][f][r]);
        if (__any(tm - m > 8.f)) {
            tm = fmaxf(tm, __shfl_xor(tm, 1));
            tm = fmaxf(tm, __shfl_xor(tm, 2));
            tm = fmaxf(tm, __shfl_xor(tm, 4));
            tm = fmaxf(tm, __shfl_xor(tm, 8));
            tm = fmaxf(tm, __shfl_xor(tm, 16));
            tm = fmaxf(tm, __shfl_xor(tm, 32));
            const float scl = __builtin_amdgcn_exp2f(m - tm);
            m = tm;
#pragma unroll
            for (int qi = 0; qi < 2; qi++) {
#pragma unroll
                for (int f = 0; f < 4; f++)
#pragma unroll
                    for (int r = 0; r < 4; r++) aco[qi][f][r] *= scl;
#pragma unroll
                for (int r = 0; r < 4; r++) aco_x[qi][r] *= scl;
            }
        }

        // P = exp2(S - m) -> bf16, packed b64 writes (slot sigma(key)=rsel*4+f)
#pragma unroll
        for (int qi = 0; qi < 2; qi++)
#pragma unroll
            for (int r = 0; r < 4; r++) {
                union { bf16 h[4]; uint64_t u; } pk4;
#pragma unroll
                for (int f = 0; f < 4; f++)
                    pk4.h[f] = (bf16)__builtin_amdgcn_exp2f(s4[qi][f][r] - m);
                *reinterpret_cast<uint64_t*>(&Psm[w][qi * 16 + csel * 4 + r][rsel * 4]) = pk4.u;
            }

        // joint PV over slot space; wave-local DS ops are in-order (no barrier)
#pragma unroll
        for (int ph = 0; ph < 2; ph++) {
            const int kc = ph * 32 + csel * 8;
            const bf16x8 pf0 = *reinterpret_cast<const bf16x8*>(&Psm[w][rsel][kc]);
            const bf16x8 pf1 = *reinterpret_cast<const bf16x8*>(&Psm[w][16 + rsel][kc]);
#pragma unroll
            for (int f2 = 0; f2 < 4; f2++) {
                aco[0][f2] = MFMA16(pf0, vf[ph][f2], aco[0][f2]);
                aco[1][f2] = MFMA16(pf1, vf[ph][f2], aco[1][f2]);
            }
            aco_x[0] = MFMA16(pf0, vones, aco_x[0]);
            aco_x[1] = MFMA16(pf1, vones, aco_x[1]);
        }
    }

    // epilogue: denominator = col 0 of aco_x; lane rsel==0 of each csel group
    const int b = bh / NHEAD, h = bh % NHEAD;
#pragma unroll
    for (int qi = 0; qi < 2; qi++) {
        float inv[4];
#pragma unroll
        for (int r = 0; r < 4; r++) inv[r] = 1.0f / __shfl(aco_x[qi][r], l & 48);
#pragma unroll
        for (int f = 0; f < 4; f++)
#pragma unroll
            for (int r = 0; r < 4; r++) {
                const int q = q0 + w * 32 + qi * 16 + csel * 4 + r;
                const int d = f * 16 + rsel;
                ctx[((size_t)b * SEQ + q) * D_MODEL + h * DK + d] = (bf16)(aco[qi][f][r] * inv[r]);
            }
    }
}

// ---------------------------------------------------------------- launcher
extern "C" void kernel_launch(void* const* d_in, const int* in_sizes, int n_in,
                              void* d_out, int out_size, void* d_ws, size_t ws_size,
                              hipStream_t stream) {
    const float* x  = (const float*)d_in[0];
    const float* Wq = (const float*)d_in[1];
    const float* bq = (const float*)d_in[2];
    const float* Wk = (const float*)d_in[3];
    const float* bk = (const float*)d_in[4];
    const float* Wv = (const float*)d_in[5];
    const float* bv = (const float*)d_in[6];
    const float* Wo = (const float*)d_in[7];
    const float* bo = (const float*)d_in[8];
    float* out = (float*)d_out;

    char* ws = (char*)d_ws;
    size_t off = 0;
    auto alloc = [&](size_t bytes) { void* p = ws + off; off += (bytes + 255) & ~(size_t)255; return p; };
    bf16* Qb   = (bf16*)alloc((size_t)BATCH * NHEAD * SEQ * DK * 2);
    bf16* Kb   = (bf16*)alloc((size_t)BATCH * NHEAD * SEQ * DK * 2);
    bf16* Vtb  = (bf16*)alloc((size_t)BATCH * NHEAD * SEQ * DK * 2);
    bf16* ctxb = (bf16*)alloc((size_t)MROWS * 768 * 2);

    gemm_qkv<<<dim3(MROWS / 128, 18), 256, 0, stream>>>(x, Wq, Wk, Wv, bq, bk, bv, Qb, Kb, Vtb);

    attn_kernel<<<dim3(SEQ / 128, BATCH * NHEAD), 256, 0, stream>>>(Qb, Kb, Vtb, ctxb);

    gemm_out<<<dim3(MROWS / 128, 768 / 128), 256, 0, stream>>>(ctxb, Wo, bo, out);
}

// Round 14
// 243.092 us; speedup vs baseline: 1.7638x; 1.7638x over previous
//
#include <hip/hip_runtime.h>
#include <hip/hip_bf16.h>
#include <cstdint>

typedef __bf16 bf16;
typedef bf16 bf16x8 __attribute__((ext_vector_type(8)));
typedef float f32x4 __attribute__((ext_vector_type(4)));

#define MFMA16(a, b, c) __builtin_amdgcn_mfma_f32_16x16x32_bf16((a), (b), (c), 0, 0, 0)

constexpr int D_MODEL = 768;
constexpr int NHEAD = 12;
constexpr int DK = 64;
constexpr int SEQ = 4096;
constexpr int BATCH = 2;
constexpr int MROWS = BATCH * SEQ;  // 8192
constexpr float QSCALE = 0.125f * 1.44269504089f;  // (1/sqrt(dk)) * log2(e)

// ---------------------------------------------------------------- fused QKV projection
// 128x128 tile, 4 waves each 64x64 (acc[4][4]). A-staging converts x fp32->bf16 in-flight.
// K and V are stored in MFMA-FRAGMENT layout so the attention kernel's per-lane 16B
// fragment loads are lane-contiguous (fully coalesced, no LDS staging needed):
//   K: elem(key s, d) -> t*4096 + (kk*4+f)*512 + l*8 + j   with t=s>>6, f=(s>>4)&3,
//      rs=s&15, kk=d>>5, cs=(d>>3)&3, j=d&7, l=cs*16+rs
//   V: slot-permuted (sigma(s)=((s&15)<<2)|((s>>4)&3) within each 64-group):
//      elem -> t*4096 + (ph*4+f2)*512 + l*8 + j  with ph=sp>>5, cs=(sp>>3)&3, j=sp&7,
//      f2=d>>4, rs=d&15, l=cs*16+rs  (P-writes pack b64 in the same slot space)
__global__ __launch_bounds__(256, 2) void gemm_qkv(const float* __restrict__ X,
                                                   const float* __restrict__ Wq,
                                                   const float* __restrict__ Wk,
                                                   const float* __restrict__ Wv,
                                                   const float* __restrict__ bq,
                                                   const float* __restrict__ bk,
                                                   const float* __restrict__ bv,
                                                   bf16* __restrict__ Qb,
                                                   bf16* __restrict__ Kb,
                                                   bf16* __restrict__ Vtb) {
    constexpr int LDP = 88;
    __shared__ bf16 Asm[128][LDP];
    __shared__ bf16 Bsm[128][LDP];
    const int tid = threadIdx.x, lane = tid & 63, wid = tid >> 6;
    const int wm = wid >> 1, wn = wid & 1;
    const int m0 = blockIdx.x * 128;
    const int sel = blockIdx.y / 6;
    const int n0 = (blockIdx.y % 6) * 128;
    const float* Bw = sel == 0 ? Wq : (sel == 1 ? Wk : Wv);
    const float* bias = sel == 0 ? bq : (sel == 1 ? bk : bv);

    f32x4 acc[4][4];
#pragma unroll
    for (int i = 0; i < 4; i++)
#pragma unroll
        for (int j = 0; j < 4; j++) acc[i][j] = f32x4{0.f, 0.f, 0.f, 0.f};

    const int rr = tid >> 3, cc = (tid & 7) * 8;
    for (int k0 = 0; k0 < 768; k0 += 64) {
#pragma unroll
        for (int p = 0; p < 4; p++) {
            const float* src = X + (size_t)(m0 + p * 32 + rr) * 768 + k0 + cc;
            const float4 f0 = *reinterpret_cast<const float4*>(src);
            const float4 f1 = *reinterpret_cast<const float4*>(src + 4);
            bf16x8 a8;
            a8[0] = (bf16)f0.x; a8[1] = (bf16)f0.y; a8[2] = (bf16)f0.z; a8[3] = (bf16)f0.w;
            a8[4] = (bf16)f1.x; a8[5] = (bf16)f1.y; a8[6] = (bf16)f1.z; a8[7] = (bf16)f1.w;
            *reinterpret_cast<bf16x8*>(&Asm[p * 32 + rr][cc]) = a8;
        }
#pragma unroll
        for (int p = 0; p < 4; p++) {
            const float* src = Bw + (size_t)(n0 + p * 32 + rr) * 768 + k0 + cc;
            const float4 f0 = *reinterpret_cast<const float4*>(src);
            const float4 f1 = *reinterpret_cast<const float4*>(src + 4);
            bf16x8 b8;
            b8[0] = (bf16)f0.x; b8[1] = (bf16)f0.y; b8[2] = (bf16)f0.z; b8[3] = (bf16)f0.w;
            b8[4] = (bf16)f1.x; b8[5] = (bf16)f1.y; b8[6] = (bf16)f1.z; b8[7] = (bf16)f1.w;
            *reinterpret_cast<bf16x8*>(&Bsm[p * 32 + rr][cc]) = b8;
        }
        __syncthreads();
#pragma unroll
        for (int kk = 0; kk < 64; kk += 32) {
            const int krd = kk + ((lane >> 4) << 3);
            bf16x8 af[4], bfr[4];
#pragma unroll
            for (int i = 0; i < 4; i++)
                af[i] = *reinterpret_cast<const bf16x8*>(&Asm[wm * 64 + i * 16 + (lane & 15)][krd]);
#pragma unroll
            for (int j = 0; j < 4; j++)
                bfr[j] = *reinterpret_cast<const bf16x8*>(&Bsm[wn * 64 + j * 16 + (lane & 15)][krd]);
#pragma unroll
            for (int i = 0; i < 4; i++)
#pragma unroll
                for (int j = 0; j < 4; j++) acc[i][j] = MFMA16(af[i], bfr[j], acc[i][j]);
        }
        __syncthreads();
    }

    const float scale = (sel == 0) ? QSCALE : 1.0f;
    const int rbase = m0 + wm * 64 + ((lane >> 4) << 2);
    const int cbase = n0 + wn * 64 + (lane & 15);
    bf16* obf = sel == 0 ? Qb : (sel == 1 ? Kb : Vtb);
#pragma unroll
    for (int i = 0; i < 4; i++) {
#pragma unroll
        for (int j = 0; j < 4; j++) {
            const int ncol = cbase + j * 16;
            const float bv = bias[ncol];
            const int h = ncol >> 6, d = ncol & 63;
#pragma unroll
            for (int r = 0; r < 4; r++) {
                const int mrow = rbase + i * 16 + r;
                const float v = (acc[i][j][r] + bv) * scale;
                const int b = mrow >> 12, s = mrow & 4095;
                const size_t hbase = ((size_t)(b * NHEAD + h)) * SEQ * DK;
                if (sel == 0) {
                    obf[hbase + (size_t)s * DK + d] = (bf16)v;
                } else if (sel == 1) {
                    // K fragment layout
                    const int tt = s >> 6, ff = (s >> 4) & 3, rs = s & 15;
                    const int kk = d >> 5, cs = (d >> 3) & 3, jj = d & 7;
                    obf[hbase + (size_t)tt * 4096 + (kk * 4 + ff) * 512 + (cs * 16 + rs) * 8 + jj] = (bf16)v;
                } else {
                    // V fragment layout (slot-permuted)
                    const int sp = ((s & 15) << 2) | ((s >> 4) & 3);
                    const int tt = s >> 6, ph = sp >> 5, cs = (sp >> 3) & 3, jj = sp & 7;
                    const int f2 = d >> 4, rs = d & 15;
                    obf[hbase + (size_t)tt * 4096 + (ph * 4 + f2) * 512 + (cs * 16 + rs) * 8 + jj] = (bf16)v;
                }
            }
        }
    }
}

// ---------------------------------------------------------------- out projection GEMM
// 128x128 tile (same fabric as gemm_qkv), fp32 epilogue with bias.
__global__ __launch_bounds__(256, 2) void gemm_out(const bf16* __restrict__ A,
                                                   const float* __restrict__ Bw,
                                                   const float* __restrict__ bias,
                                                   float* __restrict__ ofl) {
    constexpr int LDP = 88;
    __shared__ bf16 Asm[128][LDP];
    __shared__ bf16 Bsm[128][LDP];
    const int tid = threadIdx.x, lane = tid & 63, wid = tid >> 6;
    const int wm = wid >> 1, wn = wid & 1;
    const int m0 = blockIdx.x * 128, n0 = blockIdx.y * 128;

    f32x4 acc[4][4];
#pragma unroll
    for (int i = 0; i < 4; i++)
#pragma unroll
        for (int j = 0; j < 4; j++) acc[i][j] = f32x4{0.f, 0.f, 0.f, 0.f};

    const int rr = tid >> 3, cc = (tid & 7) * 8;
    for (int k0 = 0; k0 < 768; k0 += 64) {
#pragma unroll
        for (int p = 0; p < 4; p++)
            *reinterpret_cast<bf16x8*>(&Asm[p * 32 + rr][cc]) =
                *reinterpret_cast<const bf16x8*>(A + (size_t)(m0 + p * 32 + rr) * 768 + k0 + cc);
#pragma unroll
        for (int p = 0; p < 4; p++) {
            const float* src = Bw + (size_t)(n0 + p * 32 + rr) * 768 + k0 + cc;
            const float4 f0 = *reinterpret_cast<const float4*>(src);
            const float4 f1 = *reinterpret_cast<const float4*>(src + 4);
            bf16x8 b8;
            b8[0] = (bf16)f0.x; b8[1] = (bf16)f0.y; b8[2] = (bf16)f0.z; b8[3] = (bf16)f0.w;
            b8[4] = (bf16)f1.x; b8[5] = (bf16)f1.y; b8[6] = (bf16)f1.z; b8[7] = (bf16)f1.w;
            *reinterpret_cast<bf16x8*>(&Bsm[p * 32 + rr][cc]) = b8;
        }
        __syncthreads();
#pragma unroll
        for (int kk = 0; kk < 64; kk += 32) {
            const int krd = kk + ((lane >> 4) << 3);
            bf16x8 af[4], bfr[4];
#pragma unroll
            for (int i = 0; i < 4; i++)
                af[i] = *reinterpret_cast<const bf16x8*>(&Asm[wm * 64 + i * 16 + (lane & 15)][krd]);
#pragma unroll
            for (int j = 0; j < 4; j++)
                bfr[j] = *reinterpret_cast<const bf16x8*>(&Bsm[wn * 64 + j * 16 + (lane & 15)][krd]);
#pragma unroll
            for (int i = 0; i < 4; i++)
#pragma unroll
                for (int j = 0; j < 4; j++) acc[i][j] = MFMA16(af[i], bfr[j], acc[i][j]);
        }
        __syncthreads();
    }

    const int rbase = m0 + wm * 64 + ((lane >> 4) << 2);
    const int cbase = n0 + wn * 64 + (lane & 15);
#pragma unroll
    for (int i = 0; i < 4; i++) {
#pragma unroll
        for (int j = 0; j < 4; j++) {
            const int ncol = cbase + j * 16;
            const float bv = bias[ncol];
#pragma unroll
            for (int r = 0; r < 4; r++) {
                const int mrow = rbase + i * 16 + r;
                ofl[(size_t)mrow * 768 + ncol] = acc[i][j][r] + bv;
            }
        }
    }
}

// ---------------------------------------------------------------- flash attention
// R12 math with K/V in global FRAGMENT layout: every kf/vf load is 64 lanes x 16B
// CONTIGUOUS (1KB coalesced; R13's failure was 128B/lane stride = 64-line gathers).
// No K/V LDS, no staging, no prefetch registers. LDS = wave-local Psm only (18.4KB).
// One barrier per tile keeps the block's 4 waves on the same 16KB tile (L1-hot).
// vf loads issued before softmax so their latency hides under ~400cyc of VALU.
__global__ __launch_bounds__(256, 3) void attn_kernel(const bf16* __restrict__ Qb,
                                                      const bf16* __restrict__ Kfr,
                                                      const bf16* __restrict__ Vfr,
                                                      bf16* __restrict__ ctx) {
    __shared__ bf16 Psm[4][32][72];  // per-wave [q][slot]
    const int tid = threadIdx.x, l = tid & 63, w = tid >> 6;
    const int bh = blockIdx.y;
    const int q0 = blockIdx.x * 128;
    const bf16* Qh = Qb + (size_t)bh * SEQ * DK;
    const bf16* Kh = Kfr + (size_t)bh * SEQ * DK + (size_t)l * 8;  // lane-contiguous frags
    const bf16* Vh = Vfr + (size_t)bh * SEQ * DK + (size_t)l * 8;

    const int rsel = l & 15, csel = l >> 4;

    // Q fragments: 2 halves x 2 k-chunks (pre-scaled by 0.125*log2e in projection)
    bf16x8 qf[2][2];
#pragma unroll
    for (int qi = 0; qi < 2; qi++) {
        const int qr = q0 + w * 32 + qi * 16 + rsel;
#pragma unroll
        for (int kk = 0; kk < 2; kk++)
            qf[qi][kk] = *reinterpret_cast<const bf16x8*>(Qh + (size_t)qr * DK + kk * 32 + csel * 8);
    }

    // ones B-fragment: col 0 (rsel==0) = 1, else 0 -> row-sum accumulator column
    bf16x8 vones;
    {
        const bf16 ov = (rsel == 0) ? (bf16)1.0f : (bf16)0.0f;
#pragma unroll
        for (int j = 0; j < 8; j++) vones[j] = ov;
    }

    float m = -1e30f;
    f32x4 aco[2][4], aco_x[2];
#pragma unroll
    for (int qi = 0; qi < 2; qi++) {
#pragma unroll
        for (int f = 0; f < 4; f++) aco[qi][f] = f32x4{0.f, 0.f, 0.f, 0.f};
        aco_x[qi] = f32x4{0.f, 0.f, 0.f, 0.f};
    }

    constexpr int NT = SEQ / 64;
    for (int t = 0; t < NT; ++t) {
        const size_t tb = (size_t)t * 4096;

        // K fragments: 8 coalesced 1KB loads (issued first; QK^T waits only on these)
        bf16x8 kv[8];
#pragma unroll
        for (int kk = 0; kk < 2; kk++)
#pragma unroll
            for (int f = 0; f < 4; f++)
                kv[kk * 4 + f] = *reinterpret_cast<const bf16x8*>(Kh + tb + (kk * 4 + f) * 512);

        // joint QK^T: each kf feeds both halves
        f32x4 s4[2][4];
#pragma unroll
        for (int qi = 0; qi < 2; qi++)
#pragma unroll
            for (int f = 0; f < 4; f++) s4[qi][f] = f32x4{0.f, 0.f, 0.f, 0.f};
#pragma unroll
        for (int kk = 0; kk < 2; kk++) {
#pragma unroll
            for (int f = 0; f < 4; f++) {
                s4[0][f] = MFMA16(qf[0][kk], kv[kk * 4 + f], s4[0][f]);
                s4[1][f] = MFMA16(qf[1][kk], kv[kk * 4 + f], s4[1][f]);
            }
        }

        // V fragments issued NOW: latency hides under softmax VALU
        bf16x8 vv[8];
#pragma unroll
        for (int ph = 0; ph < 2; ph++)
#pragma unroll
            for (int f2 = 0; f2 < 4; f2++)
                vv[ph * 4 + f2] = *reinterpret_cast<const bf16x8*>(Vh + tb + (ph * 4 + f2) * 512);

        // lazy max: per-lane max over all 32 scores + vote; butterfly only on growth
        float tm = s4[0][0][0];
#pragma unroll
        for (int qi = 0; qi < 2; qi++)
#pragma unroll
            for (int f = 0; f < 4; f++)
#pragma unroll
                for (int r = 0; r < 4; r++) tm = fmaxf(tm, s4[qi][f][r]);
        if (__any(tm - m > 8.f)) {
            tm = fmaxf(tm, __shfl_xor(tm, 1));
            tm = fmaxf(tm, __shfl_xor(tm, 2));
            tm = fmaxf(tm, __shfl_xor(tm, 4));
            tm = fmaxf(tm, __shfl_xor(tm, 8));
            tm = fmaxf(tm, __shfl_xor(tm, 16));
            tm = fmaxf(tm, __shfl_xor(tm, 32));
            const float scl = __builtin_amdgcn_exp2f(m - tm);
            m = tm;
#pragma unroll
            for (int qi = 0; qi < 2; qi++) {
#pragma unroll
                for (int f = 0; f < 4; f++)
#pragma unroll
                    for (int r = 0; r < 4; r++) aco[qi][f][r] *= scl;
#pragma unroll
                for (int r = 0; r < 4; r++) aco_x[qi][r] *= scl;
            }
        }

        // P = exp2(S - m) -> bf16, packed b64 writes (slot sigma(key)=rsel*4+f)
#pragma unroll
        for (int qi = 0; qi < 2; qi++)
#pragma unroll
            for (int r = 0; r < 4; r++) {
                union { bf16 h[4]; uint64_t u; } pk4;
#pragma unroll
                for (int f = 0; f < 4; f++)
                    pk4.h[f] = (bf16)__builtin_amdgcn_exp2f(s4[qi][f][r] - m);
                *reinterpret_cast<uint64_t*>(&Psm[w][qi * 16 + csel * 4 + r][rsel * 4]) = pk4.u;
            }

        // joint PV over slot space; wave-local DS ops are in-order (no barrier)
#pragma unroll
        for (int ph = 0; ph < 2; ph++) {
            const int kc = ph * 32 + csel * 8;
            const bf16x8 pf0 = *reinterpret_cast<const bf16x8*>(&Psm[w][rsel][kc]);
            const bf16x8 pf1 = *reinterpret_cast<const bf16x8*>(&Psm[w][16 + rsel][kc]);
#pragma unroll
            for (int f2 = 0; f2 < 4; f2++) {
                aco[0][f2] = MFMA16(pf0, vv[ph * 4 + f2], aco[0][f2]);
                aco[1][f2] = MFMA16(pf1, vv[ph * 4 + f2], aco[1][f2]);
            }
            aco_x[0] = MFMA16(pf0, vones, aco_x[0]);
            aco_x[1] = MFMA16(pf1, vones, aco_x[1]);
        }

        __syncthreads();  // alignment only: keeps the 4 waves on the same L1-hot tile
    }

    // epilogue: denominator = col 0 of aco_x; lane rsel==0 of each csel group
    const int b = bh / NHEAD, h = bh % NHEAD;
#pragma unroll
    for (int qi = 0; qi < 2; qi++) {
        float inv[4];
#pragma unroll
        for (int r = 0; r < 4; r++) inv[r] = 1.0f / __shfl(aco_x[qi][r], l & 48);
#pragma unroll
        for (int f = 0; f < 4; f++)
#pragma unroll
            for (int r = 0; r < 4; r++) {
                const int q = q0 + w * 32 + qi * 16 + csel * 4 + r;
                const int d = f * 16 + rsel;
                ctx[((size_t)b * SEQ + q) * D_MODEL + h * DK + d] = (bf16)(aco[qi][f][r] * inv[r]);
            }
    }
}

// ---------------------------------------------------------------- launcher
extern "C" void kernel_launch(void* const* d_in, const int* in_sizes, int n_in,
                              void* d_out, int out_size, void* d_ws, size_t ws_size,
                              hipStream_t stream) {
    const float* x  = (const float*)d_in[0];
    const float* Wq = (const float*)d_in[1];
    const float* bq = (const float*)d_in[2];
    const float* Wk = (const float*)d_in[3];
    const float* bk = (const float*)d_in[4];
    const float* Wv = (const float*)d_in[5];
    const float* bv = (const float*)d_in[6];
    const float* Wo = (const float*)d_in[7];
    const float* bo = (const float*)d_in[8];
    float* out = (float*)d_out;

    char* ws = (char*)d_ws;
    size_t off = 0;
    auto alloc = [&](size_t bytes) { void* p = ws + off; off += (bytes + 255) & ~(size_t)255; return p; };
    bf16* Qb   = (bf16*)alloc((size_t)BATCH * NHEAD * SEQ * DK * 2);
    bf16* Kb   = (bf16*)alloc((size_t)BATCH * NHEAD * SEQ * DK * 2);
    bf16* Vtb  = (bf16*)alloc((size_t)BATCH * NHEAD * SEQ * DK * 2);
    bf16* ctxb = (bf16*)alloc((size_t)MROWS * 768 * 2);

    gemm_qkv<<<dim3(MROWS / 128, 18), 256, 0, stream>>>(x, Wq, Wk, Wv, bq, bk, bv, Qb, Kb, Vtb);

    attn_kernel<<<dim3(SEQ / 128, BATCH * NHEAD), 256, 0, stream>>>(Qb, Kb, Vtb, ctxb);

    gemm_out<<<dim3(MROWS / 128, 768 / 128), 256, 0, stream>>>(ctxb, Wo, bo, out);
}

// Round 15
// 215.571 us; speedup vs baseline: 1.9890x; 1.1277x over previous
//
#include <hip/hip_runtime.h>
#include <hip/hip_bf16.h>
#include <cstdint>

typedef __bf16 bf16;
typedef bf16 bf16x8 __attribute__((ext_vector_type(8)));
typedef float f32x4 __attribute__((ext_vector_type(4)));

#define MFMA16(a, b, c) __builtin_amdgcn_mfma_f32_16x16x32_bf16((a), (b), (c), 0, 0, 0)

constexpr int D_MODEL = 768;
constexpr int NHEAD = 12;
constexpr int DK = 64;
constexpr int SEQ = 4096;
constexpr int BATCH = 2;
constexpr int MROWS = BATCH * SEQ;  // 8192
constexpr float QSCALE = 0.125f * 1.44269504089f;  // (1/sqrt(dk)) * log2(e)

// ---------------------------------------------------------------- fused QKV projection
// 128x128 tile, 4 waves each 64x64 (acc[4][4]). A-staging converts x fp32->bf16 in-flight.
// K and V stored in MFMA-FRAGMENT layout (lane-contiguous 16B fragments; see R14).
__global__ __launch_bounds__(256, 2) void gemm_qkv(const float* __restrict__ X,
                                                   const float* __restrict__ Wq,
                                                   const float* __restrict__ Wk,
                                                   const float* __restrict__ Wv,
                                                   const float* __restrict__ bq,
                                                   const float* __restrict__ bk,
                                                   const float* __restrict__ bv,
                                                   bf16* __restrict__ Qb,
                                                   bf16* __restrict__ Kb,
                                                   bf16* __restrict__ Vtb) {
    constexpr int LDP = 88;
    __shared__ bf16 Asm[128][LDP];
    __shared__ bf16 Bsm[128][LDP];
    const int tid = threadIdx.x, lane = tid & 63, wid = tid >> 6;
    const int wm = wid >> 1, wn = wid & 1;
    const int m0 = blockIdx.x * 128;
    const int sel = blockIdx.y / 6;
    const int n0 = (blockIdx.y % 6) * 128;
    const float* Bw = sel == 0 ? Wq : (sel == 1 ? Wk : Wv);
    const float* bias = sel == 0 ? bq : (sel == 1 ? bk : bv);

    f32x4 acc[4][4];
#pragma unroll
    for (int i = 0; i < 4; i++)
#pragma unroll
        for (int j = 0; j < 4; j++) acc[i][j] = f32x4{0.f, 0.f, 0.f, 0.f};

    const int rr = tid >> 3, cc = (tid & 7) * 8;
    for (int k0 = 0; k0 < 768; k0 += 64) {
#pragma unroll
        for (int p = 0; p < 4; p++) {
            const float* src = X + (size_t)(m0 + p * 32 + rr) * 768 + k0 + cc;
            const float4 f0 = *reinterpret_cast<const float4*>(src);
            const float4 f1 = *reinterpret_cast<const float4*>(src + 4);
            bf16x8 a8;
            a8[0] = (bf16)f0.x; a8[1] = (bf16)f0.y; a8[2] = (bf16)f0.z; a8[3] = (bf16)f0.w;
            a8[4] = (bf16)f1.x; a8[5] = (bf16)f1.y; a8[6] = (bf16)f1.z; a8[7] = (bf16)f1.w;
            *reinterpret_cast<bf16x8*>(&Asm[p * 32 + rr][cc]) = a8;
        }
#pragma unroll
        for (int p = 0; p < 4; p++) {
            const float* src = Bw + (size_t)(n0 + p * 32 + rr) * 768 + k0 + cc;
            const float4 f0 = *reinterpret_cast<const float4*>(src);
            const float4 f1 = *reinterpret_cast<const float4*>(src + 4);
            bf16x8 b8;
            b8[0] = (bf16)f0.x; b8[1] = (bf16)f0.y; b8[2] = (bf16)f0.z; b8[3] = (bf16)f0.w;
            b8[4] = (bf16)f1.x; b8[5] = (bf16)f1.y; b8[6] = (bf16)f1.z; b8[7] = (bf16)f1.w;
            *reinterpret_cast<bf16x8*>(&Bsm[p * 32 + rr][cc]) = b8;
        }
        __syncthreads();
#pragma unroll
        for (int kk = 0; kk < 64; kk += 32) {
            const int krd = kk + ((lane >> 4) << 3);
            bf16x8 af[4], bfr[4];
#pragma unroll
            for (int i = 0; i < 4; i++)
                af[i] = *reinterpret_cast<const bf16x8*>(&Asm[wm * 64 + i * 16 + (lane & 15)][krd]);
#pragma unroll
            for (int j = 0; j < 4; j++)
                bfr[j] = *reinterpret_cast<const bf16x8*>(&Bsm[wn * 64 + j * 16 + (lane & 15)][krd]);
#pragma unroll
            for (int i = 0; i < 4; i++)
#pragma unroll
                for (int j = 0; j < 4; j++) acc[i][j] = MFMA16(af[i], bfr[j], acc[i][j]);
        }
        __syncthreads();
    }

    const float scale = (sel == 0) ? QSCALE : 1.0f;
    const int rbase = m0 + wm * 64 + ((lane >> 4) << 2);
    const int cbase = n0 + wn * 64 + (lane & 15);
    bf16* obf = sel == 0 ? Qb : (sel == 1 ? Kb : Vtb);
#pragma unroll
    for (int i = 0; i < 4; i++) {
#pragma unroll
        for (int j = 0; j < 4; j++) {
            const int ncol = cbase + j * 16;
            const float bv = bias[ncol];
            const int h = ncol >> 6, d = ncol & 63;
#pragma unroll
            for (int r = 0; r < 4; r++) {
                const int mrow = rbase + i * 16 + r;
                const float v = (acc[i][j][r] + bv) * scale;
                const int b = mrow >> 12, s = mrow & 4095;
                const size_t hbase = ((size_t)(b * NHEAD + h)) * SEQ * DK;
                if (sel == 0) {
                    obf[hbase + (size_t)s * DK + d] = (bf16)v;
                } else if (sel == 1) {
                    // K fragment layout
                    const int tt = s >> 6, ff = (s >> 4) & 3, rs = s & 15;
                    const int kk = d >> 5, cs = (d >> 3) & 3, jj = d & 7;
                    obf[hbase + (size_t)tt * 4096 + (kk * 4 + ff) * 512 + (cs * 16 + rs) * 8 + jj] = (bf16)v;
                } else {
                    // V fragment layout (slot-permuted)
                    const int sp = ((s & 15) << 2) | ((s >> 4) & 3);
                    const int tt = s >> 6, ph = sp >> 5, cs = (sp >> 3) & 3, jj = sp & 7;
                    const int f2 = d >> 4, rs = d & 15;
                    obf[hbase + (size_t)tt * 4096 + (ph * 4 + f2) * 512 + (cs * 16 + rs) * 8 + jj] = (bf16)v;
                }
            }
        }
    }
}

// ---------------------------------------------------------------- out projection GEMM
// 128x128 tile (same fabric as gemm_qkv), fp32 epilogue with bias.
__global__ __launch_bounds__(256, 2) void gemm_out(const bf16* __restrict__ A,
                                                   const float* __restrict__ Bw,
                                                   const float* __restrict__ bias,
                                                   float* __restrict__ ofl) {
    constexpr int LDP = 88;
    __shared__ bf16 Asm[128][LDP];
    __shared__ bf16 Bsm[128][LDP];
    const int tid = threadIdx.x, lane = tid & 63, wid = tid >> 6;
    const int wm = wid >> 1, wn = wid & 1;
    const int m0 = blockIdx.x * 128, n0 = blockIdx.y * 128;

    f32x4 acc[4][4];
#pragma unroll
    for (int i = 0; i < 4; i++)
#pragma unroll
        for (int j = 0; j < 4; j++) acc[i][j] = f32x4{0.f, 0.f, 0.f, 0.f};

    const int rr = tid >> 3, cc = (tid & 7) * 8;
    for (int k0 = 0; k0 < 768; k0 += 64) {
#pragma unroll
        for (int p = 0; p < 4; p++)
            *reinterpret_cast<bf16x8*>(&Asm[p * 32 + rr][cc]) =
                *reinterpret_cast<const bf16x8*>(A + (size_t)(m0 + p * 32 + rr) * 768 + k0 + cc);
#pragma unroll
        for (int p = 0; p < 4; p++) {
            const float* src = Bw + (size_t)(n0 + p * 32 + rr) * 768 + k0 + cc;
            const float4 f0 = *reinterpret_cast<const float4*>(src);
            const float4 f1 = *reinterpret_cast<const float4*>(src + 4);
            bf16x8 b8;
            b8[0] = (bf16)f0.x; b8[1] = (bf16)f0.y; b8[2] = (bf16)f0.z; b8[3] = (bf16)f0.w;
            b8[4] = (bf16)f1.x; b8[5] = (bf16)f1.y; b8[6] = (bf16)f1.z; b8[7] = (bf16)f1.w;
            *reinterpret_cast<bf16x8*>(&Bsm[p * 32 + rr][cc]) = b8;
        }
        __syncthreads();
#pragma unroll
        for (int kk = 0; kk < 64; kk += 32) {
            const int krd = kk + ((lane >> 4) << 3);
            bf16x8 af[4], bfr[4];
#pragma unroll
            for (int i = 0; i < 4; i++)
                af[i] = *reinterpret_cast<const bf16x8*>(&Asm[wm * 64 + i * 16 + (lane & 15)][krd]);
#pragma unroll
            for (int j = 0; j < 4; j++)
                bfr[j] = *reinterpret_cast<const bf16x8*>(&Bsm[wn * 64 + j * 16 + (lane & 15)][krd]);
#pragma unroll
            for (int i = 0; i < 4; i++)
#pragma unroll
                for (int j = 0; j < 4; j++) acc[i][j] = MFMA16(af[i], bfr[j], acc[i][j]);
        }
        __syncthreads();
    }

    const int rbase = m0 + wm * 64 + ((lane >> 4) << 2);
    const int cbase = n0 + wn * 64 + (lane & 15);
#pragma unroll
    for (int i = 0; i < 4; i++) {
#pragma unroll
        for (int j = 0; j < 4; j++) {
            const int ncol = cbase + j * 16;
            const float bv = bias[ncol];
#pragma unroll
            for (int r = 0; r < 4; r++) {
                const int mrow = rbase + i * 16 + r;
                ofl[(size_t)mrow * 768 + ncol] = acc[i][j][r] + bv;
            }
        }
    }
}

// ---------------------------------------------------------------- flash attention
// R14 fragment-direct fabric + software pipeline:
//   - K double-buffered in REGISTERS: tile t+1's 8 fragments prefetched during tile t
//     compute (full-tile distance hides L1/L2 latency). Loop unrolled x2 for static
//     cur/nxt roles (no runtime-indexed frag arrays -> no scratch).
//   - V issued at tile top (before QK^T), consumed after softmax.
//   - ZERO barriers in the loop (a __syncthreads would force vmcnt(0) drain and kill
//     the pipeline; Psm is wave-local so waves are fully independent).
__global__ __launch_bounds__(256, 3) void attn_kernel(const bf16* __restrict__ Qb,
                                                      const bf16* __restrict__ Kfr,
                                                      const bf16* __restrict__ Vfr,
                                                      bf16* __restrict__ ctx) {
    __shared__ bf16 Psm[4][32][72];  // per-wave [q][slot]
    const int tid = threadIdx.x, l = tid & 63, w = tid >> 6;
    const int bh = blockIdx.y;
    const int q0 = blockIdx.x * 128;
    const bf16* Qh = Qb + (size_t)bh * SEQ * DK;
    const bf16* Kh = Kfr + (size_t)bh * SEQ * DK + (size_t)l * 8;  // lane-contiguous frags
    const bf16* Vh = Vfr + (size_t)bh * SEQ * DK + (size_t)l * 8;

    const int rsel = l & 15, csel = l >> 4;

    // Q fragments: 2 halves x 2 k-chunks (pre-scaled by 0.125*log2e in projection)
    bf16x8 qf[2][2];
#pragma unroll
    for (int qi = 0; qi < 2; qi++) {
        const int qr = q0 + w * 32 + qi * 16 + rsel;
#pragma unroll
        for (int kk = 0; kk < 2; kk++)
            qf[qi][kk] = *reinterpret_cast<const bf16x8*>(Qh + (size_t)qr * DK + kk * 32 + csel * 8);
    }

    // ones B-fragment: col 0 (rsel==0) = 1, else 0 -> row-sum accumulator column
    bf16x8 vones;
    {
        const bf16 ov = (rsel == 0) ? (bf16)1.0f : (bf16)0.0f;
#pragma unroll
        for (int j = 0; j < 8; j++) vones[j] = ov;
    }

    float m = -1e30f;
    f32x4 aco[2][4], aco_x[2];
#pragma unroll
    for (int qi = 0; qi < 2; qi++) {
#pragma unroll
        for (int f = 0; f < 4; f++) aco[qi][f] = f32x4{0.f, 0.f, 0.f, 0.f};
        aco_x[qi] = f32x4{0.f, 0.f, 0.f, 0.f};
    }

    constexpr int NT = SEQ / 64;

    bf16x8 kA[8], kB[8], vv[8];
    // prologue: K tile 0 -> kA
#pragma unroll
    for (int i = 0; i < 8; i++)
        kA[i] = *reinterpret_cast<const bf16x8*>(Kh + i * 512);

    auto step = [&](bf16x8 (&kc)[8], bf16x8 (&kn)[8], int t, bool pf) {
        const size_t tb = (size_t)t * 4096;
        // V fragments for this tile (issued first; consumed after softmax)
#pragma unroll
        for (int i = 0; i < 8; i++)
            vv[i] = *reinterpret_cast<const bf16x8*>(Vh + tb + i * 512);
        // prefetch next tile's K fragments (consumed next step -> full-tile distance)
        if (pf) {
#pragma unroll
            for (int i = 0; i < 8; i++)
                kn[i] = *reinterpret_cast<const bf16x8*>(Kh + tb + 4096 + i * 512);
        }

        // joint QK^T: each kf feeds both halves
        f32x4 s4[2][4];
#pragma unroll
        for (int qi = 0; qi < 2; qi++)
#pragma unroll
            for (int f = 0; f < 4; f++) s4[qi][f] = f32x4{0.f, 0.f, 0.f, 0.f};
#pragma unroll
        for (int kk = 0; kk < 2; kk++) {
#pragma unroll
            for (int f = 0; f < 4; f++) {
                s4[0][f] = MFMA16(qf[0][kk], kc[kk * 4 + f], s4[0][f]);
                s4[1][f] = MFMA16(qf[1][kk], kc[kk * 4 + f], s4[1][f]);
            }
        }

        // lazy max: per-lane max over all 32 scores + vote; butterfly only on growth
        float tm = s4[0][0][0];
#pragma unroll
        for (int qi = 0; qi < 2; qi++)
#pragma unroll
            for (int f = 0; f < 4; f++)
#pragma unroll
                for (int r = 0; r < 4; r++) tm = fmaxf(tm, s4[qi][f][r]);
        if (__any(tm - m > 8.f)) {
            tm = fmaxf(tm, __shfl_xor(tm, 1));
            tm = fmaxf(tm, __shfl_xor(tm, 2));
            tm = fmaxf(tm, __shfl_xor(tm, 4));
            tm = fmaxf(tm, __shfl_xor(tm, 8));
            tm = fmaxf(tm, __shfl_xor(tm, 16));
            tm = fmaxf(tm, __shfl_xor(tm, 32));
            const float scl = __builtin_amdgcn_exp2f(m - tm);
            m = tm;
#pragma unroll
            for (int qi = 0; qi < 2; qi++) {
#pragma unroll
                for (int f = 0; f < 4; f++)
#pragma unroll
                    for (int r = 0; r < 4; r++) aco[qi][f][r] *= scl;
#pragma unroll
                for (int r = 0; r < 4; r++) aco_x[qi][r] *= scl;
            }
        }

        // P = exp2(S - m) -> bf16, packed b64 writes (slot sigma(key)=rsel*4+f)
#pragma unroll
        for (int qi = 0; qi < 2; qi++)
#pragma unroll
            for (int r = 0; r < 4; r++) {
                union { bf16 h[4]; uint64_t u; } pk4;
#pragma unroll
                for (int f = 0; f < 4; f++)
                    pk4.h[f] = (bf16)__builtin_amdgcn_exp2f(s4[qi][f][r] - m);
                *reinterpret_cast<uint64_t*>(&Psm[w][qi * 16 + csel * 4 + r][rsel * 4]) = pk4.u;
            }

        // joint PV over slot space; wave-local DS ops are in-order (no barrier)
#pragma unroll
        for (int ph = 0; ph < 2; ph++) {
            const int kc2 = ph * 32 + csel * 8;
            const bf16x8 pf0 = *reinterpret_cast<const bf16x8*>(&Psm[w][rsel][kc2]);
            const bf16x8 pf1 = *reinterpret_cast<const bf16x8*>(&Psm[w][16 + rsel][kc2]);
#pragma unroll
            for (int f2 = 0; f2 < 4; f2++) {
                aco[0][f2] = MFMA16(pf0, vv[ph * 4 + f2], aco[0][f2]);
                aco[1][f2] = MFMA16(pf1, vv[ph * 4 + f2], aco[1][f2]);
            }
            aco_x[0] = MFMA16(pf0, vones, aco_x[0]);
            aco_x[1] = MFMA16(pf1, vones, aco_x[1]);
        }
    };

    for (int t = 0; t < NT; t += 2) {
        step(kA, kB, t, true);
        step(kB, kA, t + 1, t + 2 < NT);
    }

    // epilogue: denominator = col 0 of aco_x; lane rsel==0 of each csel group
    const int b = bh / NHEAD, h = bh % NHEAD;
#pragma unroll
    for (int qi = 0; qi < 2; qi++) {
        float inv[4];
#pragma unroll
        for (int r = 0; r < 4; r++) inv[r] = 1.0f / __shfl(aco_x[qi][r], l & 48);
#pragma unroll
        for (int f = 0; f < 4; f++)
#pragma unroll
            for (int r = 0; r < 4; r++) {
                const int q = q0 + w * 32 + qi * 16 + csel * 4 + r;
                const int d = f * 16 + rsel;
                ctx[((size_t)b * SEQ + q) * D_MODEL + h * DK + d] = (bf16)(aco[qi][f][r] * inv[r]);
            }
    }
}

// ---------------------------------------------------------------- launcher
extern "C" void kernel_launch(void* const* d_in, const int* in_sizes, int n_in,
                              void* d_out, int out_size, void* d_ws, size_t ws_size,
                              hipStream_t stream) {
    const float* x  = (const float*)d_in[0];
    const float* Wq = (const float*)d_in[1];
    const float* bq = (const float*)d_in[2];
    const float* Wk = (const float*)d_in[3];
    const float* bk = (const float*)d_in[4];
    const float* Wv = (const float*)d_in[5];
    const float* bv = (const float*)d_in[6];
    const float* Wo = (const float*)d_in[7];
    const float* bo = (const float*)d_in[8];
    float* out = (float*)d_out;

    char* ws = (char*)d_ws;
    size_t off = 0;
    auto alloc = [&](size_t bytes) { void* p = ws + off; off += (bytes + 255) & ~(size_t)255; return p; };
    bf16* Qb   = (bf16*)alloc((size_t)BATCH * NHEAD * SEQ * DK * 2);
    bf16* Kb   = (bf16*)alloc((size_t)BATCH * NHEAD * SEQ * DK * 2);
    bf16* Vtb  = (bf16*)alloc((size_t)BATCH * NHEAD * SEQ * DK * 2);
    bf16* ctxb = (bf16*)alloc((size_t)MROWS * 768 * 2);

    gemm_qkv<<<dim3(MROWS / 128, 18), 256, 0, stream>>>(x, Wq, Wk, Wv, bq, bk, bv, Qb, Kb, Vtb);

    attn_kernel<<<dim3(SEQ / 128, BATCH * NHEAD), 256, 0, stream>>>(Qb, Kb, Vtb, ctxb);

    gemm_out<<<dim3(MROWS / 128, 768 / 128), 256, 0, stream>>>(ctxb, Wo, bo, out);
}